// Round 9
// baseline (130.741 us; speedup 1.0000x reference)
//
#include <hip/hip_runtime.h>

#define Tn 256
// Recurrence carried as u = -(10*log2e) * r  (r = DTW partial cost).
// softmin: u_new = max3(u) + log2(1 + 2^(med-max) + 2^(min-max)) - 14.4269504*cost
// cost = 0.6*om^2*dl1 pre-folded as cost_u = -8.65617024*om^2*dl1 (data-only).
// SYMMETRY: sdtw(x,y) == sdtw(y,x) exactly -> sdtw(gt,pred) not computed;
// final kernel doubles the sdtw(pred,gt) mean.
#define UBIG (-1.442695e9f)   // u-image of BIG=1e8
#define E2(v)  __builtin_amdgcn_exp2f(v)   // native v_exp_f32 (2^x)
#define LG2(v) __builtin_amdgcn_logf(v)    // native v_log_f32 (log2 x)

// One WAVE per sdtw problem (384 total), 64-thread blocks, zero sync.
// Lane t owns rows i = 4t+1 .. 4t+4. Per diagonal step:
//   - 4 independent cells (ILP hides the softmin chain)
//   - cell0's up/diag cross lanes via ONE DPP wave_shr1 (old = UBIG border)
//   - y rows stream from LDS via a 4-deep register window, prefetch dist 1
// Blocks 384..511 run the stats pass (wave-shuffle reductions).
__global__ __launch_bounds__(64) void sdtw_kernel(
    const float* __restrict__ pred, const float* __restrict__ gt,
    const float* __restrict__ mu, const float* __restrict__ lv,
    const float* __restrict__ ptc,
    const int* __restrict__ perm_gen, const int* __restrict__ perm_real,
    float* __restrict__ ws) {
  const int t = threadIdx.x;

  if (blockIdx.x >= 384) {             // ---------- stats path (1 wave) ----------
    const int b = blockIdx.x - 384;

    // KL over L=128: 2 elems/lane, then wave reduce
    const float m0 = mu[b * 128 + t],      l0 = lv[b * 128 + t];
    const float m1 = mu[b * 128 + 64 + t], l1 = lv[b * 128 + 64 + t];
    float v = (1.f + l0 - m0 * m0 - E2(l0 * 1.44269504f))
            + (1.f + l1 - m1 * m1 - E2(l1 * 1.44269504f));
    #pragma unroll
    for (int m = 32; m >= 1; m >>= 1) v += __shfl_xor(v, m);
    if (t == 0) ws[512 + b] = fmaxf(-0.5f * v - 0.5f, 0.f);

    // transition sums over 255 diffs: 4 elems/lane
    float g = 0.f, p = 0.f;
    #pragma unroll
    for (int r = 0; r < 4; ++r) {
      const int e = t + 64 * r;
      if (e < Tn - 1) {
        const float g0 = gt[(b * Tn + e) * 3 + 2];
        const float g1 = gt[(b * Tn + e + 1) * 3 + 2];
        g += fabsf(g1 - g0);
        const float q0 = pred[(b * Tn + e) * 3 + 2];
        const float q1 = pred[(b * Tn + e + 1) * 3 + 2];
        // sigmoid((q-0.5)*10) = rcp(1 + 2^(-14.4269504*(q-0.5)))
        const float s0 = __builtin_amdgcn_rcpf(1.f + E2((q0 - 0.5f) * -14.4269504f));
        const float s1 = __builtin_amdgcn_rcpf(1.f + E2((q1 - 0.5f) * -14.4269504f));
        p += fabsf(s1 - s0);
      }
    }
    #pragma unroll
    for (int m = 32; m >= 1; m >>= 1) { g += __shfl_xor(g, m); p += __shfl_xor(p, m); }
    if (t == 0) {
      const float d1 = ptc[b] - g; ws[640 + b] = d1 * d1;   // aux per-b
      const float d2 = p - g;      ws[768 + b] = d2 * d2;   // trans_reg per-b
    }
    return;
  }

  // ---------- sdtw path (3 calls: c0=(pred,gt), c1=d_gen, c2=d_real) ----------
  const int blk = blockIdx.x;
  const int c = blk >> 7;
  const int b = blk & 127;

  const float* x;
  const float* y;
  if (c == 0)      { x = pred + b * Tn * 3; y = gt   + b * Tn * 3; }
  else if (c == 1) { x = pred + b * Tn * 3; y = pred + perm_gen[b]  * Tn * 3; }
  else             { x = gt   + b * Tn * 3; y = gt   + perm_real[b] * Tn * 3; }

  // y in LDS, bank-conflict-free for the per-lane stride-4-row read:
  // row j, channel ch  ->  ysr[(j&3)*192 + ch*64 + (j>>2)]
  __shared__ float ysr[768];
  for (int k = t; k < Tn * 3; k += 64) {
    const int j = k / 3, ch = k % 3;
    ysr[(j & 3) * 192 + ch * 64 + (j >> 2)] = y[k];
  }

  // x rows 4t..4t+3 (12 floats) as 3 coalesced float4
  const float4 xa = *(const float4*)(x + 12 * t);
  const float4 xb = *(const float4*)(x + 12 * t + 4);
  const float4 xc = *(const float4*)(x + 12 * t + 8);
  const float x00 = xa.x, x01 = xa.y, x02 = xa.z;
  const float x10 = xa.w, x11 = xb.x, x12 = xb.y;
  const float x20 = xb.z, x21 = xb.w, x22 = xc.x;
  const float x30 = xc.y, x31 = xc.z, x32 = xc.w;

  __syncthreads();   // single wave: compiles to waitcnt; y staging visible

  // per-cell band windows: i = 4t+1+c ; valid d in [lo, lo+span]
  int vd0, vd1, vd2, vd3; unsigned sp0, sp1, sp2, sp3;
  {
    const int i0 = 4 * t + 1;
    #pragma unroll
    for (int cc = 0; cc < 4; ++cc) {
      const int i = i0 + cc;
      const int lo = max(i + 1, 2 * i - 150);
      const int hi = min(i + Tn, 2 * i + 150);
      const int vdi = 2 - lo; const unsigned spi = (unsigned)(hi - lo);
      if (cc == 0) { vd0 = vdi; sp0 = spi; }
      else if (cc == 1) { vd1 = vdi; sp1 = spi; }
      else if (cc == 2) { vd2 = vdi; sp2 = spi; }
      else { vd3 = vdi; sp3 = spi; }
    }
  }

  float lf0 = UBIG, lf1 = UBIG, lf2 = UBIG, lf3 = UBIG;  // u(i, d-1)
  float pp0 = UBIG, pp1 = UBIG, pp2 = UBIG;              // u(i, d-2)
  float dgv = (t == 0) ? 0.0f : UBIG;                    // u(4t, d-2) boundary

  // y register window: row for step m's cell0 lives in slot m&3.
  // Prologue fills slots 0,3,2,1 with rows q0, q0-1, q0-2, q0-3 (q0 = -4t).
  float yw0[4], yw1[4], yw2[4];
  #pragma unroll
  for (int m = 0; m >= -3; --m) {
    const int a = (m - 4 * t) & 255;
    const int pb = (a & 3) * 192 + (a >> 2);
    const int slot = m & 3;
    yw0[slot] = ysr[pb];
    yw1[slot] = ysr[pb + 64];
    yw2[slot] = ysr[pb + 128];
  }
  int qn = 1 - 4 * t;   // prefetch row index (step n loads row for step n+1)

#define CELL(X0,X1,X2, Y0,Y1,Y2, UP, LT, DG, VD, SPAN) ({                  \
    const float a0_ = (X0) - (Y0);                                         \
    const float a1_ = (X1) - (Y1);                                         \
    const float a2_ = (X2) - (Y2);                                         \
    float dl_ = fabsf(a0_) + fabsf(a1_); dl_ += fabsf(a2_);                \
    const float ex_ = E2(dl_ * -1.44269504f);                              \
    const float om_ = 1.0f - ex_;                                          \
    const float t2_ = om_ * om_ * dl_;                                     \
    const float mx_ = fmaxf(fmaxf((UP), (LT)), (DG));                      \
    const float md_ = __builtin_amdgcn_fmed3f((UP), (LT), (DG));           \
    const float mn_ = fminf(fminf((UP), (LT)), (DG));                      \
    const float s2_ = 1.0f + E2(md_ - mx_) + E2(mn_ - mx_);                \
    const float un_ = fmaf(t2_, -8.65617024f, mx_) + LG2(s2_);             \
    ((unsigned)(VD) <= (SPAN)) ? un_ : UBIG; })

#define STEP(S) do {                                                       \
    const int a_ = qn & 255;                                               \
    const int pb_ = (a_ & 3) * 192 + (a_ >> 2);                            \
    const float n0_ = ysr[pb_];                                            \
    const float n1_ = ysr[pb_ + 64];                                       \
    const float n2_ = ysr[pb_ + 128];                                      \
    qn += 1;                                                               \
    const float s_ = __int_as_float(__builtin_amdgcn_update_dpp(           \
        __float_as_int(UBIG), __float_as_int(lf3),                         \
        0x138 /*wave_shr:1*/, 0xf, 0xf, false));                           \
    const float u0_ = CELL(x00,x01,x02,                                    \
        yw0[(S) & 3],     yw1[(S) & 3],     yw2[(S) & 3],                  \
        s_,  lf0, dgv, vd0, sp0);                                          \
    const float u1_ = CELL(x10,x11,x12,                                    \
        yw0[(S + 3) & 3], yw1[(S + 3) & 3], yw2[(S + 3) & 3],              \
        lf0, lf1, pp0, vd1, sp1);                                          \
    const float u2_ = CELL(x20,x21,x22,                                    \
        yw0[(S + 2) & 3], yw1[(S + 2) & 3], yw2[(S + 2) & 3],              \
        lf1, lf2, pp1, vd2, sp2);                                          \
    const float u3_ = CELL(x30,x31,x32,                                    \
        yw0[(S + 1) & 3], yw1[(S + 1) & 3], yw2[(S + 1) & 3],              \
        lf2, lf3, pp2, vd3, sp3);                                          \
    pp0 = lf0; pp1 = lf1; pp2 = lf2;                                       \
    lf0 = u0_; lf1 = u1_; lf2 = u2_; lf3 = u3_;                            \
    dgv = s_;                                                              \
    vd0++; vd1++; vd2++; vd3++;                                            \
    yw0[(S + 1) & 3] = n0_; yw1[(S + 1) & 3] = n1_; yw2[(S + 1) & 3] = n2_;\
  } while (0)

  // 511 steps (d = 2..512): 127 unrolled groups of 4 + 3 tail steps
  #pragma unroll 1
  for (int g = 0; g < 127; ++g) {
    STEP(0); STEP(1); STEP(2); STEP(3);
  }
  STEP(0); STEP(1); STEP(2);

  // u(256,512) = lane 63 cell 3 ; r = u * -ln2/10
  if (t == 63) ws[blk] = lf3 * -0.0693147181f;
#undef STEP
#undef CELL
}

// Single block: reduce the 6 per-b arrays and emit (total, nag, kl, aux, trans_reg).
__global__ __launch_bounds__(128) void final_kernel(
    const float* __restrict__ ws, float* __restrict__ out) {
  const int t = threadIdx.x;   // 128 threads
  __shared__ float red[128];
  const int offs[6] = {0, 128, 256, 512, 640, 768};
  float sums[6];
  #pragma unroll
  for (int q = 0; q < 6; ++q) {
    red[t] = ws[offs[q] + t];
    __syncthreads();
    for (int s = 64; s > 0; s >>= 1) { if (t < s) red[t] += red[t + s]; __syncthreads(); }
    if (t == 0) sums[q] = red[0];
    __syncthreads();
  }
  if (t == 0) {
    const float inv = 1.0f / 128.0f;
    const float sim   = 2.0f * sums[0] * inv;   // sdtw(p,g)+sdtw(g,p) = 2x by symmetry
    const float dgen  = sums[1] * inv;
    const float dreal = sums[2] * inv;
    const float nag   = sim + fabsf(dgen - dreal);
    const float kl    = sums[3] * inv;
    const float aux   = sums[4] * inv;
    const float trans = sums[5] * inv;
    const float total = nag + 1.0f * kl + 0.1f * aux + 0.5f * trans;
    out[0] = total;
    out[1] = nag;
    out[2] = kl;
    out[3] = aux;
    out[4] = trans;
  }
}

extern "C" void kernel_launch(void* const* d_in, const int* in_sizes, int n_in,
                              void* d_out, int out_size, void* d_ws, size_t ws_size,
                              hipStream_t stream) {
  const float* pred = (const float*)d_in[0];   // (128,256,3)
  const float* gt   = (const float*)d_in[1];   // (128,256,3)
  const float* mu   = (const float*)d_in[2];   // (128,128)
  const float* lv   = (const float*)d_in[3];   // (128,128)
  const float* ptc  = (const float*)d_in[4];   // (128,1)
  const int*   pg   = (const int*)d_in[5];     // (128,)
  const int*   pr   = (const int*)d_in[6];     // (128,)
  float* ws  = (float*)d_ws;   // [0..383] sdtw, [512..639] kl, [640..767] aux, [768..895] trans
  float* out = (float*)d_out;  // 5 floats

  sdtw_kernel<<<512, 64, 0, stream>>>(pred, gt, mu, lv, ptc, pg, pr, ws);
  final_kernel<<<1, 128, 0, stream>>>(ws, out);
}

// Round 10
// 112.865 us; speedup vs baseline: 1.1584x; 1.1584x over previous
//
#include <hip/hip_runtime.h>

#define Tn 256
// u = -(10*log2e) * r ; softmin u' = max3 + log2(1 + 2^(med-max) + 2^(min-max)) - 14.4269504*cost
// cost folded: -8.65617024*om^2*dl1. sdtw(x,y)==sdtw(y,x) -> sim = 2*sdtw(pred,gt).
#define UBIG (-1.442695e9f)
#define E2(v)  __builtin_amdgcn_exp2f(v)
#define LG2(v) __builtin_amdgcn_logf(v)

// 2 waves per problem. Wave w owns rows 128w+1..128w+128 (2 rows/lane:
// i0=128w+2t+1, i1=i0+1). Per diagonal step: 2 cells; cross-lane via one DPP
// (lane0 <- boundary). ONE cross-wave boundary (row 128) via LDS ring,
// 16-step chunks. Wave0: d in [2,385]; wave1: d in [130,513] (384 steps each).
// y rows stored at a' = row+256 in parity-split LDS -> no wrap, no masks.
// Blocks 384..511: stats pass (wave0 only).
__global__ __launch_bounds__(128) void sdtw_kernel(
    const float* __restrict__ pred, const float* __restrict__ gt,
    const float* __restrict__ mu, const float* __restrict__ lv,
    const float* __restrict__ ptc,
    const int* __restrict__ perm_gen, const int* __restrict__ perm_real,
    float* __restrict__ ws) {
  const int t = threadIdx.x;

  if (blockIdx.x >= 384) {             // ---------- stats path (wave0 only) ----------
    if (t >= 64) return;
    const int b = blockIdx.x - 384;

    const float m0 = mu[b * 128 + t],      l0 = lv[b * 128 + t];
    const float m1 = mu[b * 128 + 64 + t], l1 = lv[b * 128 + 64 + t];
    float v = (1.f + l0 - m0 * m0 - E2(l0 * 1.44269504f))
            + (1.f + l1 - m1 * m1 - E2(l1 * 1.44269504f));
    #pragma unroll
    for (int m = 32; m >= 1; m >>= 1) v += __shfl_xor(v, m);
    if (t == 0) ws[512 + b] = fmaxf(-0.5f * v - 0.5f, 0.f);

    float g = 0.f, p = 0.f;
    #pragma unroll
    for (int r = 0; r < 4; ++r) {
      const int e = t + 64 * r;
      if (e < Tn - 1) {
        const float g0 = gt[(b * Tn + e) * 3 + 2];
        const float g1 = gt[(b * Tn + e + 1) * 3 + 2];
        g += fabsf(g1 - g0);
        const float q0 = pred[(b * Tn + e) * 3 + 2];
        const float q1 = pred[(b * Tn + e + 1) * 3 + 2];
        const float s0 = __builtin_amdgcn_rcpf(1.f + E2((q0 - 0.5f) * -14.4269504f));
        const float s1 = __builtin_amdgcn_rcpf(1.f + E2((q1 - 0.5f) * -14.4269504f));
        p += fabsf(s1 - s0);
      }
    }
    #pragma unroll
    for (int m = 32; m >= 1; m >>= 1) { g += __shfl_xor(g, m); p += __shfl_xor(p, m); }
    if (t == 0) {
      const float d1 = ptc[b] - g; ws[640 + b] = d1 * d1;
      const float d2 = p - g;      ws[768 + b] = d2 * d2;
    }
    return;
  }

  // ---------- sdtw path (c0=(pred,gt), c1=d_gen, c2=d_real) ----------
  const int blk = blockIdx.x;
  const int c = blk >> 7;
  const int b = blk & 127;

  const float* x;
  const float* y;
  if (c == 0)      { x = pred + b * Tn * 3; y = gt   + b * Tn * 3; }
  else if (c == 1) { x = pred + b * Tn * 3; y = pred + perm_gen[b]  * Tn * 3; }
  else             { x = gt   + b * Tn * 3; y = gt   + perm_real[b] * Tn * 3; }

  // y row r stored at a' = r + 256; layout [parity(a')][ch][a'>>1] (384 each).
  // All runtime indices (a'>>1) fall in [65,319] -> in-bounds, no masking.
  __shared__ float ysr[2304];
  __shared__ float rng[520];          // boundary: rng[d] = u[row 128][diag d]
  __shared__ int prog_s;
  volatile int* progp = &prog_s;

  const int wv = t >> 6;              // 0 or 1
  const int lane = t & 63;

  for (int k = t; k < Tn * 3; k += 128) {
    const int j = k / 3, ch = k % 3, ap = j + 256;
    ysr[(ap & 1) * 1152 + ch * 384 + (ap >> 1)] = y[k];
  }
  for (int k = t; k < 520; k += 128) rng[k] = UBIG;
  if (t == 0) prog_s = 0;

  const int base = wv * 128;
  const float* xp = x + (base + 2 * lane) * 3;
  const float x00 = xp[0], x01 = xp[1], x02 = xp[2];
  const float x10 = xp[3], x11 = xp[4], x12 = xp[5];

  const int i0 = base + 2 * lane + 1;
  const int i1 = i0 + 1;
  const int lo0 = max(i0 + 1, 2 * i0 - 150);
  const unsigned sp0 = (unsigned)(min(i0 + Tn, 2 * i0 + 150) - lo0);
  const int lo1 = max(i1 + 1, 2 * i1 - 150);
  const unsigned sp1 = (unsigned)(min(i1 + Tn, 2 * i1 + 150) - lo1);

  const int dstart = wv ? 130 : 2;
  int vd0 = dstart - lo0;
  int vd1 = dstart - lo1;

  __syncthreads();                    // y staged, ring init

  float lf0 = UBIG, lf1 = UBIG, pp0 = UBIG;
  float dgv;
  if (wv == 0) {
    dgv = (lane == 0) ? 0.0f : UBIG;  // r[0][0]=0 feeds cell (1,1) at d=2
  } else {
    int pv = *progp;
    while (pv < 128) { __builtin_amdgcn_s_sleep(1); pv = *progp; }
    int gi = 128;
    __asm__ volatile("" : "+v"(gi) : "v"(pv));   // order read after spin
    dgv = (lane == 0) ? rng[gi] : UBIG;          // row128 @ d=128
  }

  // carry = y row (a0 - 1), a0 = cell0 row at first step (even)
  const int a0 = dstart - base - 2 * lane - 2;
  float cr0, cr1, cr2;
  {
    const int ap = a0 - 1 + 256;
    const int pb = (ap & 1) * 1152 + (ap >> 1);
    cr0 = ysr[pb]; cr1 = ysr[pb + 384]; cr2 = ysr[pb + 768];
  }

  float res = UBIG;

#define CELL(X0,X1,X2, Y0,Y1,Y2, UP, LT, DG, VD, SPAN) ({                  \
    const float a0_ = (X0) - (Y0);                                         \
    const float a1_ = (X1) - (Y1);                                         \
    const float a2_ = (X2) - (Y2);                                         \
    float dl_ = fabsf(a0_) + fabsf(a1_); dl_ += fabsf(a2_);                \
    const float ex_ = E2(dl_ * -1.44269504f);                              \
    const float om_ = 1.0f - ex_;                                          \
    const float t2_ = om_ * om_ * dl_;                                     \
    const float mx_ = fmaxf(fmaxf((UP), (LT)), (DG));                      \
    const float md_ = __builtin_amdgcn_fmed3f((UP), (LT), (DG));           \
    const float mn_ = fminf(fminf((UP), (LT)), (DG));                      \
    const float s2_ = 1.0f + E2(md_ - mx_) + E2(mn_ - mx_);                \
    const float un_ = fmaf(t2_, -8.65617024f, mx_) + LG2(s2_);             \
    ((unsigned)(VD) <= (SPAN)) ? un_ : UBIG; })

  for (int cc = 0; cc < 24; ++cc) {
    const int cb = dstart + 16 * cc;
    const int qe = ((a0 + 16 * cc) + 256) >> 1;   // in [65,319] for all slots

    // 16 y rows for this chunk (8 even-parity, 8 odd-parity), batched reads
    float e0[8], e1[8], e2[8], o0[8], o1[8], o2[8];
    #pragma unroll
    for (int m = 0; m < 8; ++m) {
      e0[m] = ysr[qe + m];        e1[m] = ysr[384 + qe + m];  e2[m] = ysr[768 + qe + m];
      o0[m] = ysr[1152 + qe + m]; o1[m] = ysr[1536 + qe + m]; o2[m] = ysr[1920 + qe + m];
    }

    float bb[16];
    if (wv) {                         // consumer: boundary values for this chunk
      const int need = cb + 14;
      int pv = *progp;
      while (pv < need) { __builtin_amdgcn_s_sleep(1); pv = *progp; }
      int gb = cb - 1;
      __asm__ volatile("" : "+v"(gb) : "v"(pv));
      #pragma unroll
      for (int k = 0; k < 16; ++k) bb[k] = rng[gb + k];
    }

    float rr[16];
    #pragma unroll
    for (int k = 0; k < 16; ++k) {
      const int m = k >> 1;
      float ya0, ya1, ya2, yb0, yb1, yb2;
      if ((k & 1) == 0) {
        ya0 = e0[m]; ya1 = e1[m]; ya2 = e2[m];
        if (m == 0) { yb0 = cr0;     yb1 = cr1;     yb2 = cr2; }
        else        { yb0 = o0[m-1]; yb1 = o1[m-1]; yb2 = o2[m-1]; }
      } else {
        ya0 = o0[m]; ya1 = o1[m]; ya2 = o2[m];
        yb0 = e0[m]; yb1 = e1[m]; yb2 = e2[m];
      }
      const float oldv = wv ? bb[k] : UBIG;
      // up for cell0: lane-1's row i0-1 value; lane0 <- oldv
      const float s_ = __int_as_float(__builtin_amdgcn_update_dpp(
          __float_as_int(oldv), __float_as_int(lf1),
          0x138 /*wave_shr:1*/, 0xf, 0xf, false));
      const float u0 = CELL(x00, x01, x02, ya0, ya1, ya2,
                            s_,  lf0, dgv, vd0 + k, sp0);
      const float u1 = CELL(x10, x11, x12, yb0, yb1, yb2,
                            lf0, lf1, pp0, vd1 + k, sp1);
      pp0 = lf0; dgv = s_; lf0 = u0; lf1 = u1;
      rr[k] = u1;
      if (k == 14) res = u1;          // d = cb+14 ; last chunk -> d = 512
    }
    vd0 += 16; vd1 += 16;
    cr0 = o0[7]; cr1 = o1[7]; cr2 = o2[7];

    if (wv == 0) {                    // producer: publish row-128 values
      if (lane == 63) {
        #pragma unroll
        for (int k = 0; k < 16; ++k) rng[cb + k] = rr[k];
      }
      __asm__ volatile("s_waitcnt lgkmcnt(0)" ::: "memory");
      if (lane == 0) *progp = cb + 15;
    }
  }

  if (wv == 0) {                      // release: beyond d=385 ring is UBIG-init
    __asm__ volatile("s_waitcnt lgkmcnt(0)" ::: "memory");
    if (lane == 0) *progp = 0x7fffffff;
  }

  // u(256,512): wave1 lane63 cell1 at d=512 (res)
  if (t == 127) ws[blk] = res * -0.0693147181f;
#undef CELL
}

// Single block: reduce the 6 per-b arrays and emit (total, nag, kl, aux, trans_reg).
__global__ __launch_bounds__(128) void final_kernel(
    const float* __restrict__ ws, float* __restrict__ out) {
  const int t = threadIdx.x;
  __shared__ float red[128];
  const int offs[6] = {0, 128, 256, 512, 640, 768};
  float sums[6];
  #pragma unroll
  for (int q = 0; q < 6; ++q) {
    red[t] = ws[offs[q] + t];
    __syncthreads();
    for (int s = 64; s > 0; s >>= 1) { if (t < s) red[t] += red[t + s]; __syncthreads(); }
    if (t == 0) sums[q] = red[0];
    __syncthreads();
  }
  if (t == 0) {
    const float inv = 1.0f / 128.0f;
    const float sim   = 2.0f * sums[0] * inv;   // symmetry: sdtw(p,g)+sdtw(g,p)
    const float dgen  = sums[1] * inv;
    const float dreal = sums[2] * inv;
    const float nag   = sim + fabsf(dgen - dreal);
    const float kl    = sums[3] * inv;
    const float aux   = sums[4] * inv;
    const float trans = sums[5] * inv;
    const float total = nag + 1.0f * kl + 0.1f * aux + 0.5f * trans;
    out[0] = total;
    out[1] = nag;
    out[2] = kl;
    out[3] = aux;
    out[4] = trans;
  }
}

extern "C" void kernel_launch(void* const* d_in, const int* in_sizes, int n_in,
                              void* d_out, int out_size, void* d_ws, size_t ws_size,
                              hipStream_t stream) {
  const float* pred = (const float*)d_in[0];   // (128,256,3)
  const float* gt   = (const float*)d_in[1];   // (128,256,3)
  const float* mu   = (const float*)d_in[2];   // (128,128)
  const float* lv   = (const float*)d_in[3];   // (128,128)
  const float* ptc  = (const float*)d_in[4];   // (128,1)
  const int*   pg   = (const int*)d_in[5];     // (128,)
  const int*   pr   = (const int*)d_in[6];     // (128,)
  float* ws  = (float*)d_ws;   // [0..383] sdtw, [512..639] kl, [640..767] aux, [768..895] trans
  float* out = (float*)d_out;  // 5 floats

  sdtw_kernel<<<512, 128, 0, stream>>>(pred, gt, mu, lv, ptc, pg, pr, ws);
  final_kernel<<<1, 128, 0, stream>>>(ws, out);
}

// Round 11
// 105.607 us; speedup vs baseline: 1.2380x; 1.0687x over previous
//
#include <hip/hip_runtime.h>

#define Tn 256
// u = -(10*log2e)*r ; softmin u' = max3 + log2(1 + 2^(med-max) + 2^(min-max)) - 14.4269504*cost
// cost folded: -8.65617024*om^2*dl1. sdtw(x,y)==sdtw(y,x) -> sim = 2*sdtw(pred,gt).
#define UBIG (-1.442695e9f)
#define E2(v)  __builtin_amdgcn_exp2f(v)
#define LG2(v) __builtin_amdgcn_logf(v)

// 4-wave async pipeline (R7 geometry), but each wave carries TWO independent
// problems (qA=2*blk, qB=2*blk+1): their serial softmin chains interleave in
// the instruction stream and fill each other's stalls (measured: a lone wave
// issues at ~25% due to chain latency; cross-problem ILP is the only
// guaranteed filler at 384 problems / 1024 SIMDs).
// Wave w owns rows 64w+1..64w+64 (1 row/lane/problem); band windows trim
// steps; boundary rows cross waves via LDS rings + shared progress counter.
// Blocks 192..319 run the stats pass.
__global__ __launch_bounds__(256) void sdtw_kernel(
    const float* __restrict__ pred, const float* __restrict__ gt,
    const float* __restrict__ mu, const float* __restrict__ lv,
    const float* __restrict__ ptc,
    const int* __restrict__ perm_gen, const int* __restrict__ perm_real,
    float* __restrict__ ws) {
  __shared__ float yA[Tn][3], yB[Tn][3];
  __shared__ float rngA[3 * 512], rngB[3 * 512];
  __shared__ volatile int prog[4];
  __shared__ float red[256];
  __shared__ float gtr_sh;

  const int t = threadIdx.x;

  if (blockIdx.x >= 192) {             // ---------- stats path ----------
    const int b = blockIdx.x - 192;

    float v = 0.0f;
    if (t < 128) {
      const float m = mu[b * 128 + t];
      const float l = lv[b * 128 + t];
      v = 1.0f + l - m * m - E2(l * 1.44269504f);
    }
    red[t] = v; __syncthreads();
    for (int s = 128; s > 0; s >>= 1) { if (t < s) red[t] += red[t + s]; __syncthreads(); }
    if (t == 0) ws[512 + b] = fmaxf(-0.5f * red[0] - 0.5f, 0.0f);
    __syncthreads();

    float g = 0.0f;
    if (t < Tn - 1)
      g = fabsf(gt[(b * Tn + t + 1) * 3 + 2] - gt[(b * Tn + t) * 3 + 2]);
    red[t] = g; __syncthreads();
    for (int s = 128; s > 0; s >>= 1) { if (t < s) red[t] += red[t + s]; __syncthreads(); }
    if (t == 0) gtr_sh = red[0];
    __syncthreads();
    const float gtr = gtr_sh;

    float p = 0.0f;
    if (t < Tn - 1) {
      const float q0 = pred[(b * Tn + t) * 3 + 2];
      const float q1 = pred[(b * Tn + t + 1) * 3 + 2];
      const float s0 = __builtin_amdgcn_rcpf(1.f + E2((q0 - 0.5f) * -14.4269504f));
      const float s1 = __builtin_amdgcn_rcpf(1.f + E2((q1 - 0.5f) * -14.4269504f));
      p = fabsf(s1 - s0);
    }
    red[t] = p; __syncthreads();
    for (int s = 128; s > 0; s >>= 1) { if (t < s) red[t] += red[t + s]; __syncthreads(); }
    if (t == 0) {
      const float pts = red[0];
      const float d1 = ptc[b] - gtr; ws[640 + b] = d1 * d1;
      const float d2 = pts - gtr;    ws[768 + b] = d2 * d2;
    }
    return;
  }

  // ---------- sdtw path: two problems per block ----------
  const int blk = blockIdx.x;
  const int qA = 2 * blk, qB = 2 * blk + 1;   // q in [0,384): q>>7 = call, q&127 = b

  const float *xA, *yAp, *xB, *yBp;
  {
    const int cA = qA >> 7, bA = qA & 127;
    if (cA == 0)      { xA = pred + bA * Tn * 3; yAp = gt   + bA * Tn * 3; }
    else if (cA == 1) { xA = pred + bA * Tn * 3; yAp = pred + perm_gen[bA]  * Tn * 3; }
    else              { xA = gt   + bA * Tn * 3; yAp = gt   + perm_real[bA] * Tn * 3; }
    const int cB = qB >> 7, bB = qB & 127;
    if (cB == 0)      { xB = pred + bB * Tn * 3; yBp = gt   + bB * Tn * 3; }
    else if (cB == 1) { xB = pred + bB * Tn * 3; yBp = pred + perm_gen[bB]  * Tn * 3; }
    else              { xB = gt   + bB * Tn * 3; yBp = gt   + perm_real[bB] * Tn * 3; }
  }

  const int w = t >> 6;
  const int lane = t & 63;

  if (w == 0)      __builtin_amdgcn_s_setprio(3);
  else if (w == 1) __builtin_amdgcn_s_setprio(2);
  else if (w == 2) __builtin_amdgcn_s_setprio(1);

  for (int k = t; k < Tn * 3; k += 256) {
    (&yA[0][0])[k] = yAp[k];
    (&yB[0][0])[k] = yBp[k];
  }
  for (int k = t; k < 3 * 512; k += 256) { rngA[k] = UBIG; rngB[k] = UBIG; }
  if (t < 4) prog[t] = 0;

  const float xA0 = xA[t * 3], xA1 = xA[t * 3 + 1], xA2 = xA[t * 3 + 2];
  const float xB0 = xB[t * 3], xB1 = xB[t * 3 + 1], xB2 = xB[t * 3 + 2];

  const int i = t + 1;
  const int lo = max(i + 1, 2 * i - 150);
  const int hi = min(i + Tn, 2 * i + 150);
  const unsigned span = (unsigned)(hi - lo);

  const int dstart = (w == 0) ? 2 : (w == 1) ? 66 : (w == 2) ? 130 : 233;
  const int dend   = (w == 0) ? 282 : (w == 1) ? 386 : (w == 2) ? 450 : 513;
  const bool wlt3 = (w != 3);

  int cjr = dstart - t - 2;          // y row (j-1) for step k=0 of current chunk
  int vdb = dstart - lo;             // d - lo for step k=0 of current chunk

  __syncthreads();

  float lfA = UBIG, lfB = UBIG;
  float dgA, dgB;
  if (w > 0) {
    const int need0 = dstart - 2;
    int pv = prog[w - 1];
    while (pv < need0) { __builtin_amdgcn_s_sleep(1); pv = prog[w - 1]; }
    int gi = (w - 1) * 512 + dstart - 2;
    __asm__ volatile("" : "+v"(gi) : "v"(pv));
    const float rA = rngA[gi], rB = rngB[gi];
    dgA = (lane == 0) ? rA : UBIG;
    dgB = (lane == 0) ? rB : UBIG;
  } else {
    dgA = (lane == 0) ? 0.0f : UBIG;
    dgB = (lane == 0) ? 0.0f : UBIG;
  }

#define CELL(X0,X1,X2, YROW, UP, LT, DG, OK) ({                            \
    const float y0_ = (YROW)[0], y1_ = (YROW)[1], y2_ = (YROW)[2];         \
    float dl_ = fabsf((X0) - y0_) + fabsf((X1) - y1_);                     \
    dl_ += fabsf((X2) - y2_);                                              \
    const float ex_ = E2(dl_ * -1.44269504f);                              \
    const float om_ = 1.0f - ex_;                                          \
    const float t2_ = om_ * om_ * dl_;                                     \
    const float mx_ = fmaxf(fmaxf((UP), (LT)), (DG));                      \
    const float md_ = __builtin_amdgcn_fmed3f((UP), (LT), (DG));           \
    const float mn_ = fminf(fminf((UP), (LT)), (DG));                      \
    const float s2_ = 1.0f + E2(md_ - mx_) + E2(mn_ - mx_);                \
    const float un_ = fmaf(t2_, -8.65617024f, mx_) + LG2(s2_);             \
    (OK) ? un_ : UBIG; })

  for (int dbase = dstart; dbase < dend; dbase += 8) {
    float bbA[8], bbB[8];
    if (w > 0) {
      const int need = dbase + 6;
      int pv = prog[w - 1];
      while (pv < need) { __builtin_amdgcn_s_sleep(1); pv = prog[w - 1]; }
      int gb = (w - 1) * 512 + dbase - 1;
      __asm__ volatile("" : "+v"(gb) : "v"(pv));
      #pragma unroll
      for (int k = 0; k < 8; ++k) { bbA[k] = rngA[gb + k]; bbB[k] = rngB[gb + k]; }
    } else {
      #pragma unroll
      for (int k = 0; k < 8; ++k) { bbA[k] = UBIG; bbB[k] = UBIG; }
    }

    float rrA[8], rrB[8];
    #pragma unroll
    for (int k = 0; k < 8; ++k) {
      const int cj = (cjr + k) & 255;
      const bool ok = (unsigned)(vdb + k) <= span;
      const float sA = __int_as_float(__builtin_amdgcn_update_dpp(
          __float_as_int(bbA[k]), __float_as_int(lfA),
          0x138 /*wave_shr:1*/, 0xf, 0xf, false));
      const float sB = __int_as_float(__builtin_amdgcn_update_dpp(
          __float_as_int(bbB[k]), __float_as_int(lfB),
          0x138, 0xf, 0xf, false));
      const float uA = CELL(xA0, xA1, xA2, yA[cj], sA, lfA, dgA, ok);
      const float uB = CELL(xB0, xB1, xB2, yB[cj], sB, lfB, dgB, ok);
      dgA = sA; lfA = uA; rrA[k] = uA;
      dgB = sB; lfB = uB; rrB[k] = uB;
    }

    if (wlt3 && lane == 63) {
      #pragma unroll
      for (int k = 0; k < 8; ++k) {
        rngA[w * 512 + dbase + k] = rrA[k];
        rngB[w * 512 + dbase + k] = rrB[k];
      }
    }
    __asm__ volatile("s_waitcnt lgkmcnt(0)" ::: "memory");
    if (wlt3 && lane == 0) prog[w] = dbase + 7;

    cjr += 8;
    vdb += 8;
  }

  __asm__ volatile("s_waitcnt lgkmcnt(0)" ::: "memory");
  if (wlt3 && lane == 0) prog[w] = 0x7fffffff;

  // u(256,512) = wave3 lane63 lf ; r = u * -ln2/10
  if (t == 255) {
    ws[qA] = lfA * -0.0693147181f;
    ws[qB] = lfB * -0.0693147181f;
  }
#undef CELL
}

// Single block: reduce the 6 per-b arrays and emit (total, nag, kl, aux, trans_reg).
__global__ __launch_bounds__(128) void final_kernel(
    const float* __restrict__ ws, float* __restrict__ out) {
  const int t = threadIdx.x;
  __shared__ float red[128];
  const int offs[6] = {0, 128, 256, 512, 640, 768};
  float sums[6];
  #pragma unroll
  for (int q = 0; q < 6; ++q) {
    red[t] = ws[offs[q] + t];
    __syncthreads();
    for (int s = 64; s > 0; s >>= 1) { if (t < s) red[t] += red[t + s]; __syncthreads(); }
    if (t == 0) sums[q] = red[0];
    __syncthreads();
  }
  if (t == 0) {
    const float inv = 1.0f / 128.0f;
    const float sim   = 2.0f * sums[0] * inv;   // symmetry: sdtw(p,g)+sdtw(g,p)
    const float dgen  = sums[1] * inv;
    const float dreal = sums[2] * inv;
    const float nag   = sim + fabsf(dgen - dreal);
    const float kl    = sums[3] * inv;
    const float aux   = sums[4] * inv;
    const float trans = sums[5] * inv;
    const float total = nag + 1.0f * kl + 0.1f * aux + 0.5f * trans;
    out[0] = total;
    out[1] = nag;
    out[2] = kl;
    out[3] = aux;
    out[4] = trans;
  }
}

extern "C" void kernel_launch(void* const* d_in, const int* in_sizes, int n_in,
                              void* d_out, int out_size, void* d_ws, size_t ws_size,
                              hipStream_t stream) {
  const float* pred = (const float*)d_in[0];   // (128,256,3)
  const float* gt   = (const float*)d_in[1];   // (128,256,3)
  const float* mu   = (const float*)d_in[2];   // (128,128)
  const float* lv   = (const float*)d_in[3];   // (128,128)
  const float* ptc  = (const float*)d_in[4];   // (128,1)
  const int*   pg   = (const int*)d_in[5];     // (128,)
  const int*   pr   = (const int*)d_in[6];     // (128,)
  float* ws  = (float*)d_ws;   // [0..383] sdtw, [512..639] kl, [640..767] aux, [768..895] trans
  float* out = (float*)d_out;  // 5 floats

  sdtw_kernel<<<320, 256, 0, stream>>>(pred, gt, mu, lv, ptc, pg, pr, ws);
  final_kernel<<<1, 128, 0, stream>>>(ws, out);
}